// Round 11
// baseline (2132.777 us; speedup 1.0000x reference)
//
#include <hip/hip_runtime.h>
#include <hip/hip_bf16.h>

typedef unsigned short u16;
typedef unsigned int u32;
typedef unsigned long long u64;
typedef __attribute__((ext_vector_type(8))) short short8;
typedef __attribute__((ext_vector_type(4))) float floatx4;

#define I_DIM 256
#define H_DIM 1024
#define B_DIM 64
#define T_DIM 256
#define C_DIM 60
#define NWG   128
#define UPW   8      // hidden units per WG
#define BSTR  68     // pacc row stride (dwords): 16B-aligned, 2-way read aliasing

// LDS layout (bytes)
#define LDS_W_OFF    0        // 2*40*4*16 frags * 16B = 81920
#define LDS_PACC_OFF 81920    // 128 rows * 68 dw * 4B = 34816
#define LDS_BIAS_OFF 116736   // 32*4 = 128
#define LDS_CBUF_OFF 116864   // 512*4 = 2048
#define LDS_HSTG_OFF 118912   // 512*2 = 1024 (16B aligned)
#define LDS_TOTAL    119936

// workspace layout (bytes)
#define WS_XSWZ   0u          // T*B*I bf16 = 8388608
#define WS_HSWZ   8388608u    // 256 slots * 64*1024 bf16 = 33554432 (never reused)
#define WS_CNT    41943040u   // 8 counters, 256B apart = 2048
#define WS_HLAST  41945088u   // 64*1024 f32 = 262144

#define LSBM 0x0001000100010001ull

__device__ __forceinline__ u16 f2bf(float f) {
    u32 u = __float_as_uint(f);
    u32 r = (u + 0x7fffu + ((u >> 16) & 1u)) >> 16;
    return (u16)r;
}
__device__ __forceinline__ float fsig(float x) { return 1.0f / (1.0f + __expf(-x)); }
__device__ __forceinline__ float ftanh(float x) { return 2.0f * fsig(2.0f * x) - 1.0f; }

union hfrag { short8 s; u64 q[2]; };

// ---------------------------------------------------------------------------
// Pre-swizzle inputs [B][T][I] fp32 -> xswz[t] bf16 in MFMA-A-fragment layout:
// 16B unit index (per t): ((mt*8 + s)*4 + q)*16 + m  holds A[b=mt*16+m][k=s*32+q*8 .. +7]
// ---------------------------------------------------------------------------
extern "C" __global__ void prep_x(const float* __restrict__ in, u16* __restrict__ xswz) {
    int o = blockIdx.x * 256 + threadIdx.x;           // octet index, 524288 total
    int m = o & 15, q = (o >> 4) & 3, s = (o >> 6) & 7, mt = (o >> 9) & 3, t = o >> 11;
    int b = mt * 16 + m, k = s * 32 + q * 8;
    const float* src = in + ((size_t)(b * T_DIM + t)) * I_DIM + k;
    float4 v0 = *(const float4*)src;
    float4 v1 = *(const float4*)(src + 4);
    short8 val;
    val[0] = (short)f2bf(v0.x); val[1] = (short)f2bf(v0.y);
    val[2] = (short)f2bf(v0.z); val[3] = (short)f2bf(v0.w);
    val[4] = (short)f2bf(v1.x); val[5] = (short)f2bf(v1.y);
    val[6] = (short)f2bf(v1.z); val[7] = (short)f2bf(v1.w);
    *(short8*)(xswz + (size_t)o * 8) = val;
}

// ---------------------------------------------------------------------------
// Persistent LSTM scan (r11): R9 structure (ack-free publish, tags+sc-repair
// backstop, ONE polling wave per WG, barrier-gated) plus:
//  - SETTLE DELAY: after wave0 detects the gate, ~700cyc sleep before the
//    barrier releases -- lets the slowest producer's in-flight stores land
//    so the first cached L2 fill is clean (kills the r9 repair storm / L2
//    poison amplification).
//  - W B-fragments hoisted to registers (t-invariant): K-loop is pure
//    register MFMA, no per-step ds_read.
// Never-reused slots keep stale L2 hits structurally impossible; tags
// (tag=(t%13)+1, never 0=poison) close the store-in-flight race window.
// ---------------------------------------------------------------------------
extern "C" __global__ void __launch_bounds__(256, 1) lstm_scan(
    const u16* __restrict__ xswz, u16* hswz,
    const float* __restrict__ Wih, const float* __restrict__ Whh,
    const float* __restrict__ bih, const float* __restrict__ bhh,
    int* cnt8, float* hlast)
{
    extern __shared__ char lds[];
    u16*   Wlds   = (u16*)(lds + LDS_W_OFF);
    float* pacc   = (float*)(lds + LDS_PACC_OFF);
    float* bias   = (float*)(lds + LDS_BIAS_OFF);
    float* cbuf   = (float*)(lds + LDS_CBUF_OFF);
    u16*   hstage = (u16*)(lds + LDS_HSTG_OFF);

    const int j    = blockIdx.x;
    const int tid  = threadIdx.x;
    const int lane = tid & 63;
    const int w    = tid >> 6;

    // ---- stage W slice into LDS, bf16, B-swizzled (one-time):
    // unit wu = ((nt*40 + sg)*4 + q)*16 + nn  holds W[r(nt,nn)][sg*32+q*8 .. +7]
    for (int i = 0; i < 20; ++i) {
        int wu = tid + i * 256;
        int nn = wu & 15, q = (wu >> 4) & 3, rest = wu >> 6;
        int sg = rest % 40, nt = rest / 40;
        int n = nt * 16 + nn;
        int g = n >> 3, uu = n & 7;
        int r = g * H_DIM + j * UPW + uu;
        int kb = sg * 32 + q * 8;
        const float* src = (kb < I_DIM) ? (Wih + (size_t)r * I_DIM + kb)
                                        : (Whh + (size_t)r * H_DIM + (kb - I_DIM));
        short8 val;
        #pragma unroll
        for (int e = 0; e < 8; ++e) val[e] = (short)f2bf(src[e]);
        *(short8*)(Wlds + (size_t)wu * 8) = val;
    }
    if (tid < 32) {
        int n = tid, g = n >> 3, uu = n & 7;
        int r = g * H_DIM + j * UPW + uu;
        bias[n] = bih[r] + bhh[r];
    }
    for (int i = tid; i < 512; i += 256) cbuf[i] = 0.0f;
    __syncthreads();

    const int m16 = lane & 15, q4 = lane >> 4;

    // ---- hoist W B-fragments into registers (t-invariant)
    short8 breg[10][2];
    #pragma unroll
    for (int ss = 0; ss < 10; ++ss) {
        int sg = w * 10 + ss;
        breg[ss][0] = *(const short8*)(Wlds + ((((0 * 40 + sg) * 4) + q4) * 16 + m16) * 8);
        breg[ss][1] = *(const short8*)(Wlds + ((((1 * 40 + sg) * 4) + q4) * 16 + m16) * 8);
    }

    for (int t = 0; t < T_DIM; ++t) {
        const u16* xbase = xswz + (size_t)t * (B_DIM * I_DIM);
        const u16* hbase = hswz + (size_t)t * (B_DIM * H_DIM);   // fresh slot
        const int  En    = (t % 13) + 1;          // tag nibble, never 0
        const u64  Eq    = (u64)(En & 1) | ((u64)((En >> 1) & 1) << 16)
                         | ((u64)((En >> 2) & 1) << 32) | ((u64)((En >> 3) & 1) << 48);

        hfrag a[10][4];

        // ---- wave0: issue x loads FIRST (drain during poll), then poll all
        // 8 counters, then SETTLE (let slowest producer's stores land).
        if (w == 0) {
            #pragma unroll
            for (int ss = 0; ss < 8; ++ss)
                #pragma unroll
                for (int mt = 0; mt < 4; ++mt)
                    a[ss][mt].s = *(const short8*)(xbase + ((((mt * 8 + ss) * 4) + q4) * 16 + m16) * 8);
            if (t > 0) {
                int target = 16 * t;
                const int* cp = cnt8 + (lane << 6);   // lane*256 bytes
                bool need = lane < 8;
                while (true) {
                    int v = need ? __hip_atomic_load(cp, __ATOMIC_RELAXED,
                                                     __HIP_MEMORY_SCOPE_AGENT)
                                 : 0x7fffffff;
                    if (__all(v >= target)) break;
                    __builtin_amdgcn_s_sleep(1);
                }
                __builtin_amdgcn_s_sleep(11);   // settle ~700cyc (~290ns)
            }
        }
        __syncthreads();   // (C) gate passed + settled: h(t) at L3

        // ---- h-part A-frag loads, cached, upfront (deep MLP)
        if (w == 0) {
            #pragma unroll
            for (int ss = 8; ss < 10; ++ss) {
                const int sgh = ss - 8;
                #pragma unroll
                for (int mt = 0; mt < 4; ++mt)
                    a[ss][mt].s = *(const short8*)(hbase + ((((mt * 32 + sgh) * 4) + q4) * 16 + m16) * 8);
            }
        } else {
            #pragma unroll
            for (int ss = 0; ss < 10; ++ss) {
                const int sgh = w * 10 + ss - 8;
                #pragma unroll
                for (int mt = 0; mt < 4; ++mt)
                    a[ss][mt].s = *(const short8*)(hbase + ((((mt * 32 + sgh) * 4) + q4) * 16 + m16) * 8);
            }
        }

        // ---- validate tags (t>0); residual in-flight misses -> sc repair
        if (t > 0) {
            u64 m = 0;
            #pragma unroll
            for (int ss = 0; ss < 10; ++ss) {
                if (w * 10 + ss >= 8) {
                    #pragma unroll
                    for (int mt = 0; mt < 4; ++mt)
                        if ((((a[ss][mt].q[0] ^ Eq) | (a[ss][mt].q[1] ^ Eq)) & LSBM) != 0)
                            m |= 1ull << (ss * 4 + mt);
                }
            }
            while (__any(m != 0)) {
                #pragma unroll
                for (int ss = 0; ss < 10; ++ss) {
                    const int sg = w * 10 + ss;
                    if (sg >= 8) {
                        const int sgh = sg - 8;
                        #pragma unroll
                        for (int mt = 0; mt < 4; ++mt)
                            if ((m >> (ss * 4 + mt)) & 1) {
                                const u64* p = (const u64*)hbase
                                    + ((((mt * 32 + sgh) * 4) + q4) * 16 + m16) * 2;
                                a[ss][mt].q[0] = __hip_atomic_load(p,     __ATOMIC_RELAXED, __HIP_MEMORY_SCOPE_AGENT);
                                a[ss][mt].q[1] = __hip_atomic_load(p + 1, __ATOMIC_RELAXED, __HIP_MEMORY_SCOPE_AGENT);
                            }
                    }
                }
                #pragma unroll
                for (int ss = 0; ss < 10; ++ss) {
                    if (w * 10 + ss >= 8) {
                        #pragma unroll
                        for (int mt = 0; mt < 4; ++mt)
                            if (((m >> (ss * 4 + mt)) & 1) &&
                                ((((a[ss][mt].q[0] ^ Eq) | (a[ss][mt].q[1] ^ Eq)) & LSBM) == 0))
                                m &= ~(1ull << (ss * 4 + mt));
                    }
                }
            }
        }

        // ---- MFMA loop: pure register compute
        floatx4 acc[4][2];
        #pragma unroll
        for (int mt = 0; mt < 4; ++mt)
            #pragma unroll
            for (int nt = 0; nt < 2; ++nt)
                acc[mt][nt] = (floatx4){0.f, 0.f, 0.f, 0.f};

        #pragma unroll
        for (int ss = 0; ss < 10; ++ss)
            #pragma unroll
            for (int mt = 0; mt < 4; ++mt)
                #pragma unroll
                for (int nt = 0; nt < 2; ++nt)
                    acc[mt][nt] = __builtin_amdgcn_mfma_f32_16x16x32_bf16(
                        a[ss][mt].s, breg[ss][nt], acc[mt][nt], 0, 0, 0);

        // ---- write K-partials transposed: pacc[(w*32+n)*BSTR + b], b128 stores
        #pragma unroll
        for (int mt = 0; mt < 4; ++mt)
            #pragma unroll
            for (int nt = 0; nt < 2; ++nt)
                *(floatx4*)(pacc + (w * 32 + nt * 16 + m16) * BSTR + mt * 16 + q4 * 4) =
                    acc[mt][nt];
        __syncthreads();   // (A) pacc ready

        // ---- pointwise: reduce partials, gates, c/h update -> hstage (tagged)
        const int Ep = ((t + 1) % 13) + 1;
        #pragma unroll
        for (int it = 0; it < 2; ++it) {
            int idx = tid + it * 256;       // (b, uu)
            int b = idx >> 3, uu = idx & 7;
            float s[4];
            #pragma unroll
            for (int g = 0; g < 4; ++g) {
                int n = g * 8 + uu;
                float v = bias[n];
                #pragma unroll
                for (int ww = 0; ww < 4; ++ww) v += pacc[(ww * 32 + n) * BSTR + b];
                s[g] = v;
            }
            float ig = fsig(s[0]), fg = fsig(s[1]), gg = ftanh(s[2]), og = fsig(s[3]);
            float c = fg * cbuf[b * 8 + uu] + ig * gg;
            cbuf[b * 8 + uu] = c;
            float h = og * ftanh(c);
            // steal lsb: tag bit (uu&3) of next step's nibble
            hstage[b * 8 + uu] = (u16)((f2bf(h) & 0xFFFEu) | ((Ep >> (uu & 3)) & 1));
            if (t == T_DIM - 1) hlast[b * H_DIM + j * UPW + uu] = h;
        }
        __syncthreads();   // (B) hstage ready; pacc free for next step

        // ---- publish: wave0 sc-stores h(t+1), then fetch_add IMMEDIATELY
        // (ack-free; settle delay + tags close the race window)
        if (tid < 64 && t + 1 < T_DIM) {
            int b = tid;
            const u64* hs = (const u64*)hstage;
            u64 lo = hs[b * 2], hi = hs[b * 2 + 1];
            u16* hw = hswz + (size_t)(t + 1) * (B_DIM * H_DIM);
            // unit octet: ((mt*32 + (j>>2))*4 + (j&3))*16 + mm, mt=b>>4, mm=b&15
            u64* dst = (u64*)hw + ((((b >> 4) * 32 + (j >> 2)) * 4 + (j & 3)) * 16 + (b & 15)) * 2;
            __hip_atomic_store(dst,     lo, __ATOMIC_RELAXED, __HIP_MEMORY_SCOPE_AGENT);
            __hip_atomic_store(dst + 1, hi, __ATOMIC_RELAXED, __HIP_MEMORY_SCOPE_AGENT);
            if (tid == 0)
                __hip_atomic_fetch_add(cnt8 + ((j >> 4) << 6), 1, __ATOMIC_RELAXED,
                                       __HIP_MEMORY_SCOPE_AGENT);
        }
    }
}

// ---------------------------------------------------------------------------
// FC + log_softmax: one wave per batch row. logits[b][c] = h.fc_w[c] + fc_b[c]
// ---------------------------------------------------------------------------
extern "C" __global__ void fc_logsoftmax(const float* __restrict__ hlast,
                                         const float* __restrict__ fcw,
                                         const float* __restrict__ fcb,
                                         float* __restrict__ out)
{
    int b = blockIdx.x, c = threadIdx.x;  // 64 threads, 1 wave
    float acc = 0.0f;
    if (c < C_DIM) {
        const float* wr = fcw + (size_t)c * H_DIM;
        const float* hr = hlast + (size_t)b * H_DIM;
        for (int k = 0; k < H_DIM; k += 4) {
            float4 hv = *(const float4*)(hr + k);
            float4 wv = *(const float4*)(wr + k);
            acc += hv.x * wv.x + hv.y * wv.y + hv.z * wv.z + hv.w * wv.w;
        }
        acc += fcb[c];
    }
    float logit = (c < C_DIM) ? acc : -1e30f;
    float mx = logit;
    #pragma unroll
    for (int off = 32; off; off >>= 1) mx = fmaxf(mx, __shfl_xor(mx, off));
    float e = (c < C_DIM) ? expf(logit - mx) : 0.0f;
    float sum = e;
    #pragma unroll
    for (int off = 32; off; off >>= 1) sum += __shfl_xor(sum, off);
    if (c < C_DIM) out[b * C_DIM + c] = logit - mx - logf(sum);
}

extern "C" void kernel_launch(void* const* d_in, const int* in_sizes, int n_in,
                              void* d_out, int out_size, void* d_ws, size_t ws_size,
                              hipStream_t stream)
{
    const float* inputs = (const float*)d_in[0];
    const float* Wih    = (const float*)d_in[1];
    const float* Whh    = (const float*)d_in[2];
    const float* bih    = (const float*)d_in[3];
    const float* bhh    = (const float*)d_in[4];
    const float* fcw    = (const float*)d_in[5];
    const float* fcb    = (const float*)d_in[6];
    float* out = (float*)d_out;

    char* ws = (char*)d_ws;
    u16*   xswz  = (u16*)(ws + WS_XSWZ);
    u16*   hswz  = (u16*)(ws + WS_HSWZ);
    int*   cnt8  = (int*)(ws + WS_CNT);
    float* hlast = (float*)(ws + WS_HLAST);

    // slot 0 = h_0 = 0 (t=0 skips tag check); counters = 0. Slots t>=1 keep
    // harness poison 0xAA whose tag nibble is 0 -> never validates early.
    hipMemsetAsync(hswz, 0, B_DIM * H_DIM * sizeof(u16), stream);
    hipMemsetAsync(cnt8, 0, 2048, stream);

    prep_x<<<2048, 256, 0, stream>>>(inputs, xswz);

    (void)hipFuncSetAttribute((const void*)lstm_scan,
                              hipFuncAttributeMaxDynamicSharedMemorySize, LDS_TOTAL);
    lstm_scan<<<NWG, 256, LDS_TOTAL, stream>>>(xswz, hswz, Wih, Whh, bih, bhh,
                                               cnt8, hlast);
    fc_logsoftmax<<<B_DIM, 64, 0, stream>>>(hlast, fcw, fcb, out);
}

// Round 12
// 1510.437 us; speedup vs baseline: 1.4120x; 1.4120x over previous
//
#include <hip/hip_runtime.h>
#include <hip/hip_bf16.h>

typedef unsigned short u16;
typedef unsigned int u32;
typedef unsigned long long u64;
typedef __attribute__((ext_vector_type(8))) short short8;
typedef __attribute__((ext_vector_type(4))) float floatx4;

#define I_DIM 256
#define H_DIM 1024
#define B_DIM 64
#define T_DIM 256
#define C_DIM 60
#define NWG   128
#define UPW   8      // hidden units per WG
#define BSTR  68     // pacc row stride (dwords): 16B-aligned, 2-way read aliasing

// LDS layout (bytes)
#define LDS_W_OFF    0        // 2*40*4*16 frags * 16B = 81920
#define LDS_PACC_OFF 81920    // 128 rows * 68 dw * 4B = 34816
#define LDS_BIAS_OFF 116736   // 32*4 = 128
#define LDS_CBUF_OFF 116864   // 512*4 = 2048
#define LDS_TOTAL    118912

// workspace layout (bytes)
#define WS_XSWZ   0u          // T*B*I bf16 = 8388608
#define WS_HSWZ   8388608u    // 256 slots * 64*1024 bf16 = 33554432 (never reused)
#define WS_CNT    41943040u   // 8 counters, 256B apart = 2048
#define WS_HLAST  41945088u   // 64*1024 f32 = 262144

__device__ __forceinline__ u16 f2bf(float f) {
    u32 u = __float_as_uint(f);
    u32 r = (u + 0x7fffu + ((u >> 16) & 1u)) >> 16;
    return (u16)r;
}
__device__ __forceinline__ float fsig(float x) { return 1.0f / (1.0f + __expf(-x)); }
__device__ __forceinline__ float ftanh(float x) { return 2.0f * fsig(2.0f * x) - 1.0f; }

// ---------------------------------------------------------------------------
// Pre-swizzle inputs [B][T][I] fp32 -> xswz[t] bf16 in MFMA-A-fragment layout:
// 16B unit index (per t): ((mt*8 + s)*4 + q)*16 + m  holds A[b=mt*16+m][k=s*32+q*8 .. +7]
// ---------------------------------------------------------------------------
extern "C" __global__ void prep_x(const float* __restrict__ in, u16* __restrict__ xswz) {
    int o = blockIdx.x * 256 + threadIdx.x;           // octet index, 524288 total
    int m = o & 15, q = (o >> 4) & 3, s = (o >> 6) & 7, mt = (o >> 9) & 3, t = o >> 11;
    int b = mt * 16 + m, k = s * 32 + q * 8;
    const float* src = in + ((size_t)(b * T_DIM + t)) * I_DIM + k;
    float4 v0 = *(const float4*)src;
    float4 v1 = *(const float4*)(src + 4);
    short8 val;
    val[0] = (short)f2bf(v0.x); val[1] = (short)f2bf(v0.y);
    val[2] = (short)f2bf(v0.z); val[3] = (short)f2bf(v0.w);
    val[4] = (short)f2bf(v1.x); val[5] = (short)f2bf(v1.y);
    val[6] = (short)f2bf(v1.z); val[7] = (short)f2bf(v1.w);
    *(short8*)(xswz + (size_t)o * 8) = val;
}

// ---------------------------------------------------------------------------
// Persistent LSTM scan (r12): GATED CACHED BROADCAST, NEVER-REUSED SLOTS,
// FUSED REGISTER PUBLISH.
// - PRECISE gate (adds only after each wave's own stores drained) => every
//   consumer cached load is a clean compulsory L2 miss filled from L3.
//   No tags, no repair, no lsb noise. (R8-proven safety.)
// - Publish fused into pointwise: each thread (b, dword-pair) computes its
//   2 h elems and issues ONE 4B relaxed agent atomic store from registers
//   (coalesced 256B/wave). No hstage, no repack, barrier B deleted.
// - Per-wave release: s_waitcnt vmcnt(0) per wave, lane0 fetch_add; gate
//   target 64*t (4 adds/WG/step). Drains overlap across waves and WGs.
// - ONE polling wave (wave0), polls all 8 counters; barrier C gates the WG.
//   wave0 issues its x loads before polling (drain during poll).
// ---------------------------------------------------------------------------
extern "C" __global__ void __launch_bounds__(256, 1) lstm_scan(
    const u16* __restrict__ xswz, u16* hswz,
    const float* __restrict__ Wih, const float* __restrict__ Whh,
    const float* __restrict__ bih, const float* __restrict__ bhh,
    int* cnt8, float* hlast)
{
    extern __shared__ char lds[];
    u16*   Wlds   = (u16*)(lds + LDS_W_OFF);
    float* pacc   = (float*)(lds + LDS_PACC_OFF);
    float* bias   = (float*)(lds + LDS_BIAS_OFF);
    float* cbuf   = (float*)(lds + LDS_CBUF_OFF);

    const int j    = blockIdx.x;
    const int tid  = threadIdx.x;
    const int lane = tid & 63;
    const int w    = tid >> 6;

    // ---- stage W slice into LDS, bf16, B-swizzled (one-time):
    // unit wu = ((nt*40 + sg)*4 + q)*16 + nn  holds W[r(nt,nn)][sg*32+q*8 .. +7]
    for (int i = 0; i < 20; ++i) {
        int wu = tid + i * 256;
        int nn = wu & 15, q = (wu >> 4) & 3, rest = wu >> 6;
        int sg = rest % 40, nt = rest / 40;
        int n = nt * 16 + nn;
        int g = n >> 3, uu = n & 7;
        int r = g * H_DIM + j * UPW + uu;
        int kb = sg * 32 + q * 8;
        const float* src = (kb < I_DIM) ? (Wih + (size_t)r * I_DIM + kb)
                                        : (Whh + (size_t)r * H_DIM + (kb - I_DIM));
        short8 val;
        #pragma unroll
        for (int e = 0; e < 8; ++e) val[e] = (short)f2bf(src[e]);
        *(short8*)(Wlds + (size_t)wu * 8) = val;
    }
    if (tid < 32) {
        int n = tid, g = n >> 3, uu = n & 7;
        int r = g * H_DIM + j * UPW + uu;
        bias[n] = bih[r] + bhh[r];
    }
    for (int i = tid; i < 512; i += 256) cbuf[i] = 0.0f;
    __syncthreads();

    const int m16 = lane & 15, q4 = lane >> 4;
    const int pb = tid >> 2, pp = tid & 3;        // pointwise (b, dword-pair)

    for (int t = 0; t < T_DIM; ++t) {
        const u16* xbase = xswz + (size_t)t * (B_DIM * I_DIM);
        const u16* hbase = hswz + (size_t)t * (B_DIM * H_DIM);   // fresh slot

        short8 a[10][4];

        // ---- wave0: issue x loads FIRST (drain during poll), then poll gate
        if (w == 0) {
            #pragma unroll
            for (int ss = 0; ss < 8; ++ss)
                #pragma unroll
                for (int mt = 0; mt < 4; ++mt)
                    a[ss][mt] = *(const short8*)(xbase + ((((mt * 8 + ss) * 4) + q4) * 16 + m16) * 8);
            if (t > 0) {
                int target = 64 * t;              // 4 waves x 16 WGs per group
                const int* cp = cnt8 + (lane << 6);   // lane*256 bytes
                bool need = lane < 8;
                while (true) {
                    int v = need ? __hip_atomic_load(cp, __ATOMIC_RELAXED,
                                                     __HIP_MEMORY_SCOPE_AGENT)
                                 : 0x7fffffff;
                    if (__all(v >= target)) break;
                    __builtin_amdgcn_s_sleep(1);
                }
            }
        }
        __syncthreads();   // (C) gate passed: h(t) fully at L3

        // ---- h-part A-frag loads, cached (L2-shared per XCD), deep MLP
        if (w == 0) {
            #pragma unroll
            for (int ss = 8; ss < 10; ++ss) {
                const int sgh = ss - 8;
                #pragma unroll
                for (int mt = 0; mt < 4; ++mt)
                    a[ss][mt] = *(const short8*)(hbase + ((((mt * 32 + sgh) * 4) + q4) * 16 + m16) * 8);
            }
        } else {
            #pragma unroll
            for (int ss = 0; ss < 10; ++ss) {
                const int sgh = w * 10 + ss - 8;
                #pragma unroll
                for (int mt = 0; mt < 4; ++mt)
                    a[ss][mt] = *(const short8*)(hbase + ((((mt * 32 + sgh) * 4) + q4) * 16 + m16) * 8);
            }
        }

        // ---- MFMA loop (B frags from LDS — t-invariant layout, no spills)
        floatx4 acc[4][2];
        #pragma unroll
        for (int mt = 0; mt < 4; ++mt)
            #pragma unroll
            for (int nt = 0; nt < 2; ++nt)
                acc[mt][nt] = (floatx4){0.f, 0.f, 0.f, 0.f};

        #pragma unroll
        for (int ss = 0; ss < 10; ++ss) {
            int sg = w * 10 + ss;
            short8 b[2];
            #pragma unroll
            for (int nt = 0; nt < 2; ++nt)
                b[nt] = *(const short8*)(Wlds + ((((nt * 40 + sg) * 4) + q4) * 16 + m16) * 8);
            #pragma unroll
            for (int mt = 0; mt < 4; ++mt)
                #pragma unroll
                for (int nt = 0; nt < 2; ++nt)
                    acc[mt][nt] = __builtin_amdgcn_mfma_f32_16x16x32_bf16(
                        a[ss][mt], b[nt], acc[mt][nt], 0, 0, 0);
        }

        // ---- write K-partials transposed: pacc[(w*32+n)*BSTR + b], b128 stores
        #pragma unroll
        for (int mt = 0; mt < 4; ++mt)
            #pragma unroll
            for (int nt = 0; nt < 2; ++nt)
                *(floatx4*)(pacc + (w * 32 + nt * 16 + m16) * BSTR + mt * 16 + q4 * 4) =
                    acc[mt][nt];
        __syncthreads();   // (A) pacc ready

        // ---- pointwise + FUSED publish: thread (pb, pp) computes h elems
        // uu = 2*pp, 2*pp+1 for batch row pb, stores one packed dword.
        {
            float hv[2];
            #pragma unroll
            for (int e = 0; e < 2; ++e) {
                int uu = pp * 2 + e;
                float s[4];
                #pragma unroll
                for (int g = 0; g < 4; ++g) {
                    int n = g * 8 + uu;
                    float v = bias[n];
                    #pragma unroll
                    for (int ww = 0; ww < 4; ++ww) v += pacc[(ww * 32 + n) * BSTR + pb];
                    s[g] = v;
                }
                float ig = fsig(s[0]), fg = fsig(s[1]), gg = ftanh(s[2]), og = fsig(s[3]);
                float c = fg * cbuf[pb * 8 + uu] + ig * gg;
                cbuf[pb * 8 + uu] = c;
                hv[e] = og * ftanh(c);
            }
            if (t + 1 < T_DIM) {
                u32 val = (u32)f2bf(hv[0]) | ((u32)f2bf(hv[1]) << 16);
                u16* hw = hswz + (size_t)(t + 1) * (B_DIM * H_DIM);
                // 16B unit per (j,b): ((mt*32+(j>>2))*4+(j&3))*16+mm; dword pp
                u32* dst = (u32*)hw
                    + ((((pb >> 4) * 32 + (j >> 2)) * 4 + (j & 3)) * 16 + (pb & 15)) * 4 + pp;
                __hip_atomic_store(dst, val, __ATOMIC_RELAXED, __HIP_MEMORY_SCOPE_AGENT);
                // per-wave release: own stores drained -> one add per wave
                asm volatile("s_waitcnt vmcnt(0)" ::: "memory");
                if (lane == 0)
                    __hip_atomic_fetch_add(cnt8 + ((j >> 4) << 6), 1, __ATOMIC_RELAXED,
                                           __HIP_MEMORY_SCOPE_AGENT);
            } else {
                hlast[pb * H_DIM + j * UPW + pp * 2]     = hv[0];
                hlast[pb * H_DIM + j * UPW + pp * 2 + 1] = hv[1];
            }
        }
        // no barrier here: next step's pacc writes happen only after
        // barrier (C), which every wave reaches after finishing pointwise(t).
    }
}

// ---------------------------------------------------------------------------
// FC + log_softmax: one wave per batch row. logits[b][c] = h.fc_w[c] + fc_b[c]
// ---------------------------------------------------------------------------
extern "C" __global__ void fc_logsoftmax(const float* __restrict__ hlast,
                                         const float* __restrict__ fcw,
                                         const float* __restrict__ fcb,
                                         float* __restrict__ out)
{
    int b = blockIdx.x, c = threadIdx.x;  // 64 threads, 1 wave
    float acc = 0.0f;
    if (c < C_DIM) {
        const float* wr = fcw + (size_t)c * H_DIM;
        const float* hr = hlast + (size_t)b * H_DIM;
        for (int k = 0; k < H_DIM; k += 4) {
            float4 hv = *(const float4*)(hr + k);
            float4 wv = *(const float4*)(wr + k);
            acc += hv.x * wv.x + hv.y * wv.y + hv.z * wv.z + hv.w * wv.w;
        }
        acc += fcb[c];
    }
    float logit = (c < C_DIM) ? acc : -1e30f;
    float mx = logit;
    #pragma unroll
    for (int off = 32; off; off >>= 1) mx = fmaxf(mx, __shfl_xor(mx, off));
    float e = (c < C_DIM) ? expf(logit - mx) : 0.0f;
    float sum = e;
    #pragma unroll
    for (int off = 32; off; off >>= 1) sum += __shfl_xor(sum, off);
    if (c < C_DIM) out[b * C_DIM + c] = logit - mx - logf(sum);
}

extern "C" void kernel_launch(void* const* d_in, const int* in_sizes, int n_in,
                              void* d_out, int out_size, void* d_ws, size_t ws_size,
                              hipStream_t stream)
{
    const float* inputs = (const float*)d_in[0];
    const float* Wih    = (const float*)d_in[1];
    const float* Whh    = (const float*)d_in[2];
    const float* bih    = (const float*)d_in[3];
    const float* bhh    = (const float*)d_in[4];
    const float* fcw    = (const float*)d_in[5];
    const float* fcb    = (const float*)d_in[6];
    float* out = (float*)d_out;

    char* ws = (char*)d_ws;
    u16*   xswz  = (u16*)(ws + WS_XSWZ);
    u16*   hswz  = (u16*)(ws + WS_HSWZ);
    int*   cnt8  = (int*)(ws + WS_CNT);
    float* hlast = (float*)(ws + WS_HLAST);

    // slot 0 = h_0 = 0; counters = 0. Kernel-boundary release makes these
    // visible to all cached readers. Slots t>=1 are written before any read
    // (precise gate), so poison is never observed.
    hipMemsetAsync(hswz, 0, B_DIM * H_DIM * sizeof(u16), stream);
    hipMemsetAsync(cnt8, 0, 2048, stream);

    prep_x<<<2048, 256, 0, stream>>>(inputs, xswz);

    (void)hipFuncSetAttribute((const void*)lstm_scan,
                              hipFuncAttributeMaxDynamicSharedMemorySize, LDS_TOTAL);
    lstm_scan<<<NWG, 256, LDS_TOTAL, stream>>>(xswz, hswz, Wih, Whh, bih, bhh,
                                               cnt8, hlast);
    fc_logsoftmax<<<B_DIM, 64, 0, stream>>>(hlast, fcw, fcb, out);
}